// Round 2
// baseline (428.348 us; speedup 1.0000x reference)
//
#include <hip/hip_runtime.h>

// DEQ fused kernel, round 2: BARRIER-FREE iteration loop.
//
// out = relu^{(30)}(z Wz^T + inj) @ Wd^T + bd,  inj = x Ux^T + b
//
// Each wave owns 16 batch rows and the FULL hidden dim (n=128):
//   - Wz lives in registers as 8x4 A-fragments (128 VGPRs, iteration-invariant)
//   - D[n][m] = sum_k Wz[n][k] Z^T[k][m]: output register axis = n = next
//     iteration's k axis -> packed ds_write_b64 store / ds_read_b128 load,
//     wave-PRIVATE LDS region, no __syncthreads anywhere in the loop.
//   - 8 independent accumulation chains (nt=0..7) of depth 4 per iteration
//     keep the per-SIMD matrix pipe full at 2 waves/SIMD.

typedef __attribute__((ext_vector_type(8))) __bf16 bf16x8;
typedef __attribute__((ext_vector_type(4))) __bf16 bf16x4;
typedef __attribute__((ext_vector_type(4))) float  floatx4;

#define MFMA16(a, b, c) __builtin_amdgcn_mfma_f32_16x16x32_bf16((a), (b), (c), 0, 0, 0)

static constexpr int kBsz = 262144;
static constexpr int kTM  = 64;    // batch rows per block (16 per wave)
static constexpr int kLdsStride = 136;  // bf16; 272 B = 68 dwords per row

__device__ __forceinline__ bf16x8 cvt_bf16x8(float4 a, float4 b) {
  bf16x8 r;
  r[0] = (__bf16)a.x; r[1] = (__bf16)a.y; r[2] = (__bf16)a.z; r[3] = (__bf16)a.w;
  r[4] = (__bf16)b.x; r[5] = (__bf16)b.y; r[6] = (__bf16)b.z; r[7] = (__bf16)b.w;
  return r;
}

__global__ void __launch_bounds__(256, 2) deq_fused(
    const float* __restrict__ x,    // [B,64]
    const float* __restrict__ Wz,   // [128,128]
    const float* __restrict__ Ux,   // [128,64]
    const float* __restrict__ bvec, // [128]
    const float* __restrict__ Wd,   // [64,128]
    const float* __restrict__ bd,   // [64]
    const int*  __restrict__ n_iters_p,
    float* __restrict__ out)        // [B,64]
{
  // wave-private z tiles: 4 waves x 16 rows x 136 bf16 (single-buffered;
  // same-wave DS ops are in-order so RAW/WAR within a wave need no barrier)
  __shared__ __align__(16) __bf16 zl[4][16][kLdsStride];

  const int tid  = threadIdx.x;
  const int lane = tid & 63;
  const int wv   = tid >> 6;   // 0..3, owns rows [16*wv, 16*wv+16) of block tile
  const int l15  = lane & 15;
  const int quad = lane >> 4;  // 0..3
  const int grow = blockIdx.x * kTM + 16 * wv + l15;  // this lane's batch row (as m / N-axis)
  const int iters = *n_iters_p;

  __bf16* zrow = &zl[wv][l15][0];  // this lane's private z row base

  // ---- inj in C/D layout: reg i -> n = 16nt + 4quad + i, col(lane&15) -> m ----
  floatx4 inj[8];
#pragma unroll
  for (int nt = 0; nt < 8; ++nt) {
    const float4 bv = *(const float4*)(bvec + 16 * nt + 4 * quad);
    floatx4 v = {bv.x, bv.y, bv.z, bv.w};
    inj[nt] = v;
  }
  {
    // encoder: inj += Ux @ x^T   (A = Ux, M-axis = n, K = 64 -> 2 k-steps)
#pragma unroll
    for (int ks = 0; ks < 2; ++ks) {
      const float4* px = (const float4*)(x + (size_t)grow * 64 + 32 * ks + 8 * quad);
      const bf16x8 bx = cvt_bf16x8(px[0], px[1]);
#pragma unroll
      for (int nt = 0; nt < 8; ++nt) {
        const int n = 16 * nt + l15;
        const float4* p = (const float4*)(Ux + n * 64 + 32 * ks + 8 * quad);
        inj[nt] = MFMA16(cvt_bf16x8(p[0], p[1]), bx, inj[nt]);
      }
    }
  }

  // ---- Wz as A-fragments (iteration-invariant, register-resident) ----
  // A[n][k]: n = 16*nt + l15, k = 32*ks + 8*quad + j
  bf16x8 awz[8][4];
#pragma unroll
  for (int nt = 0; nt < 8; ++nt) {
    const int n = 16 * nt + l15;
#pragma unroll
    for (int ks = 0; ks < 4; ++ks) {
      const float4* p = (const float4*)(Wz + n * 128 + 32 * ks + 8 * quad);
      awz[nt][ks] = cvt_bf16x8(p[0], p[1]);
    }
  }

  // ---- z1 = relu(inj) (z0 = 0) -> packed b64 writes into private rows ----
#pragma unroll
  for (int nt = 0; nt < 8; ++nt) {
    bf16x4 z4;
#pragma unroll
    for (int i = 0; i < 4; ++i) z4[i] = (__bf16)fmaxf(inj[nt][i], 0.0f);
    *(bf16x4*)&zrow[16 * nt + 4 * quad] = z4;
  }

  // ---- fixed-point loop: NO barriers ----
#pragma unroll 1
  for (int t = 0; t < iters - 1; ++t) {
    // Z^T B-frags: B[k][m], k contiguous in the row -> ds_read_b128
    bf16x8 bz[4];
#pragma unroll
    for (int ks = 0; ks < 4; ++ks)
      bz[ks] = *(const bf16x8*)&zrow[32 * ks + 8 * quad];
    floatx4 acc[8];
#pragma unroll
    for (int nt = 0; nt < 8; ++nt) {
      acc[nt] = inj[nt];
#pragma unroll
      for (int ks = 0; ks < 4; ++ks)
        acc[nt] = MFMA16(awz[nt][ks], bz[ks], acc[nt]);
    }
#pragma unroll
    for (int nt = 0; nt < 8; ++nt) {
      bf16x4 z4;
#pragma unroll
      for (int i = 0; i < 4; ++i) z4[i] = (__bf16)fmaxf(acc[nt][i], 0.0f);
      *(bf16x4*)&zrow[16 * nt + 4 * quad] = z4;
    }
  }

  // ---- decoder: D[o][m] = sum_k Wd[o][k] Z^T[k][m] + bd ----
  {
    bf16x8 bz[4];
#pragma unroll
    for (int ks = 0; ks < 4; ++ks)
      bz[ks] = *(const bf16x8*)&zrow[32 * ks + 8 * quad];
#pragma unroll
    for (int ot = 0; ot < 4; ++ot) {
      const int o = 16 * ot + l15;
      const float4 bv = *(const float4*)(bd + 16 * ot + 4 * quad);
      floatx4 acc = {bv.x, bv.y, bv.z, bv.w};
#pragma unroll
      for (int ks = 0; ks < 4; ++ks) {
        const float4* p = (const float4*)(Wd + o * 128 + 32 * ks + 8 * quad);
        acc = MFMA16(cvt_bf16x8(p[0], p[1]), bz[ks], acc);
      }
      // D col = lane&15 = m (this lane's grow), reg i -> o consecutive
      float4 ov;
      ov.x = acc[0]; ov.y = acc[1]; ov.z = acc[2]; ov.w = acc[3];
      *(float4*)(out + (size_t)grow * 64 + 16 * ot + 4 * quad) = ov;
    }
  }
}

extern "C" void kernel_launch(void* const* d_in, const int* in_sizes, int n_in,
                              void* d_out, int out_size, void* d_ws, size_t ws_size,
                              hipStream_t stream) {
  const float* x  = (const float*)d_in[0];
  const float* Wz = (const float*)d_in[1];
  const float* Ux = (const float*)d_in[2];
  const float* b  = (const float*)d_in[3];
  const float* Wd = (const float*)d_in[4];
  const float* bd = (const float*)d_in[5];
  const int* n_it = (const int*)d_in[6];
  float* out = (float*)d_out;
  (void)in_sizes; (void)n_in; (void)d_ws; (void)ws_size; (void)out_size;

  dim3 grid(kBsz / kTM);  // 4096 blocks, 4 independent waves each
  deq_fused<<<grid, 256, 0, stream>>>(x, Wz, Ux, b, Wd, bd, n_it, out);
}

// Round 3
// 349.344 us; speedup vs baseline: 1.2262x; 1.2262x over previous
//
#include <hip/hip_runtime.h>

// DEQ fused kernel, round 3: round-1 structure (276us) + XOR-swizzled pow-2 LDS.
//
// out = relu^{(30)}(z Wz^T + inj) @ Wd^T + bd,  inj = x Ux^T + b
//
// Wave decomposition (round-1): 4 waves/block, wn = n-half (64 hid units),
// wm = m-half (32 of 64 batch rows). Wz half in registers (awz[4][4], 64 VGPR).
// D[n][m] = sum_k Wz[n][k] Z^T[k][m]: D's register axis = n = next iteration's
// k axis -> packed ds_write_b64 stores / ds_read_b128 loads. One barrier/iter
// (double buffer).
//
// Round-3 change: z tile row stride = 128 bf16 (pow2), with 16B-chunk XOR
// swizzle  chunk_store = chunk ^ (m&7).
//   reads:  any contiguous <=16-lane phase has uniform quad -> XOR by l15&7
//           permutes the 8 four-bank groups -> ZERO read conflicts.
//   writes: only l15 vs l15+8 alias -> 2-way, which is free on gfx950.
// LDS drops 34816 -> 32768 B/block -> 5 blocks/CU by LDS (was ~2.5 resident).

typedef __attribute__((ext_vector_type(8))) __bf16 bf16x8;
typedef __attribute__((ext_vector_type(4))) __bf16 bf16x4;
typedef __attribute__((ext_vector_type(4))) float  floatx4;

#define MFMA16(a, b, c) __builtin_amdgcn_mfma_f32_16x16x32_bf16((a), (b), (c), 0, 0, 0)

static constexpr int kBsz = 262144;
static constexpr int kTM  = 64;    // batch rows per block

__device__ __forceinline__ bf16x8 cvt_bf16x8(float4 a, float4 b) {
  bf16x8 r;
  r[0] = (__bf16)a.x; r[1] = (__bf16)a.y; r[2] = (__bf16)a.z; r[3] = (__bf16)a.w;
  r[4] = (__bf16)b.x; r[5] = (__bf16)b.y; r[6] = (__bf16)b.z; r[7] = (__bf16)b.w;
  return r;
}

// swizzled bf16-index of (row m, k-chunk c, extra bf16 offset within chunk)
__device__ __forceinline__ int zidx(int m, int c, int off) {
  return m * 128 + 8 * (c ^ (m & 7)) + off;
}

__global__ void __launch_bounds__(256) deq_fused(
    const float* __restrict__ x,    // [B,64]
    const float* __restrict__ Wz,   // [128,128]
    const float* __restrict__ Ux,   // [128,64]
    const float* __restrict__ bvec, // [128]
    const float* __restrict__ Wd,   // [64,128]
    const float* __restrict__ bd,   // [64]
    const int*  __restrict__ n_iters_p,
    float* __restrict__ out)        // [B,64]
{
  // double-buffered z tile, swizzled row-major [m][k], stride 128 bf16
  __shared__ __align__(16) __bf16 zl[2][kTM * 128];

  const int tid  = threadIdx.x;
  const int lane = tid & 63;
  const int wv   = tid >> 6;   // 0..3
  const int wn   = wv & 1;     // n-half: hid units [64*wn, 64*wn+64)
  const int wm   = wv >> 1;    // m-half: rows [32*wm, 32*wm+32) of block tile
  const int l15  = lane & 15;
  const int quad = lane >> 4;  // 0..3
  const int row0 = blockIdx.x * kTM;
  const int iters = *n_iters_p;

  // ---- Wz half as A-fragments (iteration-invariant, 64 VGPRs) ----
  // A[n][k]: n = 64*wn + 16*nt + l15, k = 32*ks + 8*quad + j
  bf16x8 awz[4][4];
#pragma unroll
  for (int nt = 0; nt < 4; ++nt) {
    const int n = 64 * wn + 16 * nt + l15;
#pragma unroll
    for (int ks = 0; ks < 4; ++ks) {
      const float4* p = (const float4*)(Wz + n * 128 + 32 * ks + 8 * quad);
      awz[nt][ks] = cvt_bf16x8(p[0], p[1]);
    }
  }

  // ---- inj in C/D layout: reg i -> n = 64wn+16nt+4quad+i, col -> m ----
  floatx4 inj[4][2];
#pragma unroll
  for (int nt = 0; nt < 4; ++nt) {
    const float4 bv = *(const float4*)(bvec + 64 * wn + 16 * nt + 4 * quad);
#pragma unroll
    for (int mt = 0; mt < 2; ++mt) {
      floatx4 v = {bv.x, bv.y, bv.z, bv.w};
      inj[nt][mt] = v;
    }
  }
  {
    // encoder: inj += Ux @ x^T  (K=64 -> 2 k-steps)
    bf16x8 aux[4][2];
#pragma unroll
    for (int nt = 0; nt < 4; ++nt) {
      const int n = 64 * wn + 16 * nt + l15;
#pragma unroll
      for (int ks = 0; ks < 2; ++ks) {
        const float4* p = (const float4*)(Ux + n * 64 + 32 * ks + 8 * quad);
        aux[nt][ks] = cvt_bf16x8(p[0], p[1]);
      }
    }
#pragma unroll
    for (int mt = 0; mt < 2; ++mt) {
      const int m = row0 + 32 * wm + 16 * mt + l15;
#pragma unroll
      for (int ks = 0; ks < 2; ++ks) {
        const float4* p = (const float4*)(x + (size_t)m * 64 + 32 * ks + 8 * quad);
        const bf16x8 bx = cvt_bf16x8(p[0], p[1]);
#pragma unroll
        for (int nt = 0; nt < 4; ++nt)
          inj[nt][mt] = MFMA16(aux[nt][ks], bx, inj[nt][mt]);
      }
    }
  }

  // ---- z1 = relu(inj) (z0 = 0) -> buffer 0, swizzled b64 writes ----
  // n = 64wn + 16nt + 4quad : chunk = 8wn + 2nt + (quad>>1), off = 4*(quad&1)
#pragma unroll
  for (int mt = 0; mt < 2; ++mt) {
    const int ml = 32 * wm + 16 * mt + l15;
#pragma unroll
    for (int nt = 0; nt < 4; ++nt) {
      bf16x4 z4;
#pragma unroll
      for (int i = 0; i < 4; ++i) z4[i] = (__bf16)fmaxf(inj[nt][mt][i], 0.0f);
      *(bf16x4*)&zl[0][zidx(ml, 8 * wn + 2 * nt + (quad >> 1), 4 * (quad & 1))] = z4;
    }
  }

  // ---- fixed-point loop: 1 barrier per iteration (double buffer) ----
  int pb = 0;
  for (int t = 0; t < iters - 1; ++t) {
    __syncthreads();
    // Z^T B-frags: B[k][m], k = 32ks + 8quad + j -> chunk 4ks+quad, b128 reads
    bf16x8 bz[2][4];
#pragma unroll
    for (int mt = 0; mt < 2; ++mt) {
      const int ml = 32 * wm + 16 * mt + l15;
#pragma unroll
      for (int ks = 0; ks < 4; ++ks)
        bz[mt][ks] = *(const bf16x8*)&zl[pb][zidx(ml, 4 * ks + quad, 0)];
    }
    const int nb = pb ^ 1;
#pragma unroll
    for (int mt = 0; mt < 2; ++mt) {
      const int ml = 32 * wm + 16 * mt + l15;
#pragma unroll
      for (int nt = 0; nt < 4; ++nt) {
        floatx4 acc = inj[nt][mt];
#pragma unroll
        for (int ks = 0; ks < 4; ++ks)
          acc = MFMA16(awz[nt][ks], bz[mt][ks], acc);
        bf16x4 z4;
#pragma unroll
        for (int i = 0; i < 4; ++i) z4[i] = (__bf16)fmaxf(acc[i], 0.0f);
        *(bf16x4*)&zl[nb][zidx(ml, 8 * wn + 2 * nt + (quad >> 1), 4 * (quad & 1))] = z4;
      }
    }
    pb = nb;
  }
  __syncthreads();

  // ---- decoder: D[o][m] = sum_k Wd[o][k] Z^T[k][m] + bd ----
  bf16x8 awd[2][4];
#pragma unroll
  for (int ot = 0; ot < 2; ++ot) {
    const int o = 32 * wn + 16 * ot + l15;
#pragma unroll
    for (int ks = 0; ks < 4; ++ks) {
      const float4* p = (const float4*)(Wd + o * 128 + 32 * ks + 8 * quad);
      awd[ot][ks] = cvt_bf16x8(p[0], p[1]);
    }
  }
#pragma unroll
  for (int mt = 0; mt < 2; ++mt) {
    const int ml = 32 * wm + 16 * mt + l15;
    bf16x8 bz[4];
#pragma unroll
    for (int ks = 0; ks < 4; ++ks)
      bz[ks] = *(const bf16x8*)&zl[pb][zidx(ml, 4 * ks + quad, 0)];
#pragma unroll
    for (int ot = 0; ot < 2; ++ot) {
      const float4 bv = *(const float4*)(bd + 32 * wn + 16 * ot + 4 * quad);
      floatx4 acc = {bv.x, bv.y, bv.z, bv.w};
#pragma unroll
      for (int ks = 0; ks < 4; ++ks)
        acc = MFMA16(awd[ot][ks], bz[ks], acc);
      float4 ov;
      ov.x = acc[0]; ov.y = acc[1]; ov.z = acc[2]; ov.w = acc[3];
      *(float4*)(out + (size_t)(row0 + ml) * 64 + 32 * wn + 16 * ot + 4 * quad) = ov;
    }
  }
}

extern "C" void kernel_launch(void* const* d_in, const int* in_sizes, int n_in,
                              void* d_out, int out_size, void* d_ws, size_t ws_size,
                              hipStream_t stream) {
  const float* x  = (const float*)d_in[0];
  const float* Wz = (const float*)d_in[1];
  const float* Ux = (const float*)d_in[2];
  const float* b  = (const float*)d_in[3];
  const float* Wd = (const float*)d_in[4];
  const float* bd = (const float*)d_in[5];
  const int* n_it = (const int*)d_in[6];
  float* out = (float*)d_out;
  (void)in_sizes; (void)n_in; (void)d_ws; (void)ws_size; (void)out_size;

  dim3 grid(kBsz / kTM);  // 4096 blocks
  deq_fused<<<grid, 256, 0, stream>>>(x, Wz, Ux, b, Wd, bd, n_it, out);
}